// Round 1
// baseline (2229.821 us; speedup 1.0000x reference)
//
#include <hip/hip_runtime.h>
#include <math.h>

#define HH 256
#define WW 512
#define CC 768
#define KW 129            // kept W modes (0..128)
#define NB 8
#define BS 96
#define MPC (KW*HH)       // modes per channel = 33024
#define K3M 64            // modes per K3 block

constexpr float SF = 0.00276213586400528f;   // 1/sqrt(131072)  forward ortho
constexpr float SI = 0.00552427172801056f;   // 2/sqrt(131072)  inverse ortho (x2 from packing)
constexpr float LAM = 0.01f;

// XOR swizzle for the 256-entry FFT buffers: kills the 8-way write conflicts of
// early Stockham stages while keeping contiguous runs >=16 conflict-free.
#define SWZ(i) ((i) ^ (((i) >> 4) & 0xF))
// Swizzle for the [k][r] transpose tile (stride-8-float2 access across k lanes
// was a 16-way conflict): spread bits 4..7 into bits 1..3 and bit 7 into bit 0.
#define TSWZ(i) ((i) ^ ((((i) >> 4) & 7) << 1) ^ (((i) >> 7) & 1))

__device__ inline float2 cadd(float2 a, float2 b) { return make_float2(a.x + b.x, a.y + b.y); }
__device__ inline float2 csub(float2 a, float2 b) { return make_float2(a.x - b.x, a.y - b.y); }
__device__ inline float2 cmul(float2 a, float2 b) {
    return make_float2(a.x * b.x - a.y * b.y, a.x * b.y + a.y * b.x);
}

// ---------------------------------------------------------------------------
// Twiddle table: radix-2 stage s in [0,8), m = 128>>s entries,
// tw[off(s)+p] = e^{sign*2*pi*i*p/(256>>s)}.  off = 0,128,192,224,240,248,252,254.
// Generated once per block (255 sincos total, vs 1024 per FFT row before).
// ---------------------------------------------------------------------------
__device__ inline void gen_tw(float2* tw, int tid, int nthr, float sign) {
    for (int f = tid; f < 255; f += nthr) {
        int fm = f, n = 256;
        while (fm >= (n >> 1)) { fm -= (n >> 1); n >>= 1; }
        float sn, cs;
        __sincosf(sign * 6.283185307179586f * (float)fm / (float)n, &sn, &cs);
        tw[f] = make_float2(cs, sn);
    }
}

// ---------------------------------------------------------------------------
// 256-point Stockham FFT, two radix-2 stages fused per pass (register radix-4):
// stage s writes {d1, d1+ls, d1+128, d1+128+ls} which are exactly stage s+1's
// read pairs, so the pair runs entirely in registers. 4 barriers instead of 8,
// half the LDS traffic. One 64-lane wave per row; result lands in s0.
// Twiddle sign is baked into the table.
// ---------------------------------------------------------------------------
__device__ inline void fft256x4(float2* s0, float2* s1, const float2* tw, int lane) {
    float2* src = s0;
    float2* dst = s1;
    int logls = 0;
    int offA = 0;
#pragma unroll
    for (int j = 0; j < 4; j++) {
        int ls = 1 << logls;            // 1,4,16,64
        int hm = 64 >> logls;           // 64/ls = entries of stage B
        int offB = offA + (128 >> logls);
        int q = lane & (ls - 1);
        int p = lane >> logls;
        float2 a0 = src[SWZ(lane)];
        float2 a1 = src[SWZ(lane + 64)];
        float2 a2 = src[SWZ(lane + 128)];
        float2 a3 = src[SWZ(lane + 192)];
        float2 wA0 = tw[offA + p];
        float2 wA1 = tw[offA + p + hm];
        float2 wB  = tw[offB + p];
        // stage A (n = 256>>2j): butterflies at lane and lane+64
        float2 e0 = cadd(a0, a2);
        float2 e1 = cmul(csub(a0, a2), wA0);
        float2 e2 = cadd(a1, a3);
        float2 e3 = cmul(csub(a1, a3), wA1);
        // stage B (n/2): butterflies at d1 and d1+ls, both twiddle index p
        float2 f0 = cadd(e0, e2);
        float2 f1 = cmul(csub(e0, e2), wB);
        float2 f2 = cadd(e1, e3);
        float2 f3 = cmul(csub(e1, e3), wB);
        int o = q + ((p << logls) << 2);  // q + 4*p*ls
        dst[SWZ(o)]          = f0;
        dst[SWZ(o + ls)]     = f2;
        dst[SWZ(o + 2 * ls)] = f1;
        dst[SWZ(o + 3 * ls)] = f3;
        __syncthreads();
        float2* tmp = src; src = dst; dst = tmp;
        offA = offB + hm;
        logls += 2;
    }
}

// ---------------------------------------------------------------------------
// K1: forward real FFT along W (512 real -> 129 complex), packed-real trick.
// 8 rows (one wave each) per block; swizzled LDS tile-transpose so the output
// A[c][k][h] (h contiguous) is written in 64B chunks.
// ---------------------------------------------------------------------------
__global__ __launch_bounds__(512) void k1_rfftw(const float* __restrict__ x,
                                                float2* __restrict__ A) {
    __shared__ float2 b0[8][256];
    __shared__ float2 b1[8][256];
    __shared__ float2 tile[KW * 8];
    __shared__ float2 tw[255];
    __shared__ float2 ctw[129];

    int tid = threadIdx.x;
    gen_tw(tw, tid, 512, -1.0f);
    for (int f = tid; f < 129; f += 512) {
        float sn, cs;
        __sincosf(-6.283185307179586f * (float)f / 512.0f, &sn, &cs);
        ctw[f] = make_float2(cs, sn);
    }

    int r = tid >> 6;            // row 0..7 (= wave id)
    int lane = tid & 63;
    int blk = blockIdx.x;        // 0..24575
    int c = blk >> 5;            // channel
    int h0 = (blk & 31) << 3;    // first h of this block
    int h = h0 + r;

    const float4* xrow = (const float4*)(x + ((size_t)c * HH + h) * WW);
    float2* s0 = b0[r];
    float2* s1 = b1[r];

    // pack: z[n] = x[2n] + i x[2n+1], scaled by forward ortho factor
    for (int n = lane; n < 128; n += 64) {
        float4 v = xrow[n];
        s0[SWZ(2 * n)]     = make_float2(v.x * SF, v.y * SF);
        s0[SWZ(2 * n + 1)] = make_float2(v.z * SF, v.w * SF);
    }
    __syncthreads();

    fft256x4(s0, s1, tw, lane);

    // combine to X[k], k = 0..128
    for (int k = lane; k <= 128; k += 64) {
        float2 Za = s0[SWZ(k & 255)];
        float2 Zb = s0[SWZ((256 - k) & 255)];
        // Xe = 0.5(Za + conj(Zb)); Xo = -0.5i(Za - conj(Zb))
        float2 Xe = make_float2(0.5f * (Za.x + Zb.x), 0.5f * (Za.y - Zb.y));
        float dx = Za.x - Zb.x;
        float dy = Za.y + Zb.y;
        float2 Xo = make_float2(0.5f * dy, -0.5f * dx);
        float2 X = cadd(Xe, cmul(Xo, ctw[k]));
        tile[TSWZ(k * 8 + r)] = X;
    }
    __syncthreads();

    for (int idx = tid; idx < KW * 8; idx += 512) {
        int k = idx >> 3;
        int r2 = idx & 7;
        A[((size_t)c * KW + k) * HH + h0 + r2] = tile[TSWZ(idx)];
    }
}

// ---------------------------------------------------------------------------
// K2/K4: 256-pt complex FFT along H, in place. A flat = [c][k][h], each column
// is 256 contiguous float2. 4 columns (one wave each) per 256-thread block.
// ---------------------------------------------------------------------------
template <int SIGN>
__global__ __launch_bounds__(256) void k_colfft(float2* __restrict__ A) {
    __shared__ float2 b0[4][256];
    __shared__ float2 b1[4][256];
    __shared__ float2 tw[255];
    int tid = threadIdx.x;
    gen_tw(tw, tid, 256, (float)SIGN);
    int col = tid >> 6;          // 0..3 (= wave id)
    int lane = tid & 63;
    size_t base = ((size_t)blockIdx.x * 4 + col) * 256;
    float2* s0 = b0[col];
    float2* s1 = b1[col];
    const float4* Ai = (const float4*)(A + base);
    for (int n = lane; n < 128; n += 64) {
        float4 v = Ai[n];
        s0[SWZ(2 * n)]     = make_float2(v.x, v.y);
        s0[SWZ(2 * n + 1)] = make_float2(v.z, v.w);
    }
    __syncthreads();
    fft256x4(s0, s1, tw, lane);
    float4* Ao = (float4*)(A + base);
    for (int n = lane; n < 128; n += 64) {
        float2 z0 = s0[SWZ(2 * n)];
        float2 z1 = s0[SWZ(2 * n + 1)];
        Ao[n] = make_float4(z0.x, z0.y, z1.x, z1.y);
    }
}

// ---------------------------------------------------------------------------
// K3: per-mode complex MLP, in place on A. One block = one channel-block bk and
// 64 modes; 512 threads = 8 waves, wave w owns output rows o = rr*16+w, +8 →
// o is wave-uniform so weights go through the SCALAR pipe (readfirstlane →
// s_load), and each LDS a-read feeds 8 FMAs (2 outputs register-blocked).
// Single 48 KB tile reused for a then hidden → 3 blocks/CU.
// ---------------------------------------------------------------------------
__global__ __launch_bounds__(512) void k3_mlp(float2* __restrict__ A,
                                              const float2* __restrict__ w1,
                                              const float2* __restrict__ b1,
                                              const float2* __restrict__ w2,
                                              const float2* __restrict__ b2) {
    __shared__ float2 tile[BS][K3M];   // 96 x 64 complex = 48 KB, reused
    int tid = threadIdx.x;
    int bk = blockIdx.x / (MPC / K3M);           // 0..7
    int m0 = (blockIdx.x % (MPC / K3M)) * K3M;   // mode tile origin
    int t = tid & 63;
    int osub = tid >> 6;    // 0..7, wave-uniform

    for (int idx = tid; idx < BS * (K3M / 2); idx += 512) {
        int i = idx >> 5;
        int tt = idx & 31;
        float4 v = *(const float4*)(A + ((size_t)(bk * BS + i)) * MPC + m0 + 2 * tt);
        tile[i][2 * tt]     = make_float2(v.x, v.y);
        tile[i][2 * tt + 1] = make_float2(v.z, v.w);
    }
    __syncthreads();

    const float2* w1b = w1 + (size_t)bk * BS * BS;
    const float2* b1b = b1 + (size_t)bk * BS;
    const float2* w2b = w2 + (size_t)bk * BS * BS;
    const float2* b2b = b2 + (size_t)bk * BS;

    float2 hreg[12];
#pragma unroll
    for (int rr = 0; rr < 6; rr++) {
        int o1 = __builtin_amdgcn_readfirstlane(rr * 16 + osub);
        int o2 = o1 + 8;
        float2 acc1 = b1b[o1];
        float2 acc2 = b1b[o2];
#pragma unroll 8
        for (int i = 0; i < BS; i++) {
            float2 a = tile[i][t];
            float2 wA = w1b[i * BS + o1];
            float2 wB = w1b[i * BS + o2];
            acc1.x = fmaf(a.x, wA.x, fmaf(-a.y, wA.y, acc1.x));
            acc1.y = fmaf(a.x, wA.y, fmaf(a.y, wA.x, acc1.y));
            acc2.x = fmaf(a.x, wB.x, fmaf(-a.y, wB.y, acc2.x));
            acc2.y = fmaf(a.x, wB.y, fmaf(a.y, wB.x, acc2.y));
        }
        hreg[2 * rr]     = make_float2(fmaxf(acc1.x, 0.f), fmaxf(acc1.y, 0.f));
        hreg[2 * rr + 1] = make_float2(fmaxf(acc2.x, 0.f), fmaxf(acc2.y, 0.f));
    }
    __syncthreads();
#pragma unroll
    for (int rr = 0; rr < 6; rr++) {
        tile[rr * 16 + osub][t]     = hreg[2 * rr];
        tile[rr * 16 + 8 + osub][t] = hreg[2 * rr + 1];
    }
    __syncthreads();

#pragma unroll
    for (int rr = 0; rr < 6; rr++) {
        int o1 = __builtin_amdgcn_readfirstlane(rr * 16 + osub);
        int o2 = o1 + 8;
        float2 acc1 = b2b[o1];
        float2 acc2 = b2b[o2];
#pragma unroll 8
        for (int i = 0; i < BS; i++) {
            float2 a = tile[i][t];
            float2 wA = w2b[i * BS + o1];
            float2 wB = w2b[i * BS + o2];
            acc1.x = fmaf(a.x, wA.x, fmaf(-a.y, wA.y, acc1.x));
            acc1.y = fmaf(a.x, wA.y, fmaf(a.y, wA.x, acc1.y));
            acc2.x = fmaf(a.x, wB.x, fmaf(-a.y, wB.y, acc2.x));
            acc2.y = fmaf(a.x, wB.y, fmaf(a.y, wB.x, acc2.y));
        }
        float r1x = fmaxf(fabsf(acc1.x) - LAM, 0.f);
        float r1y = fmaxf(fabsf(acc1.y) - LAM, 0.f);
        float r2x = fmaxf(fabsf(acc2.x) - LAM, 0.f);
        float r2y = fmaxf(fabsf(acc2.y) - LAM, 0.f);
        float2 s1v = make_float2(copysignf(r1x, acc1.x), copysignf(r1y, acc1.y));
        float2 s2v = make_float2(copysignf(r2x, acc2.x), copysignf(r2y, acc2.y));
        A[((size_t)(bk * BS + o1)) * MPC + m0 + t] = s1v;
        A[((size_t)(bk * BS + o2)) * MPC + m0 + t] = s2v;
    }
}

// ---------------------------------------------------------------------------
// K5: inverse real FFT along W (129 complex modes, rest zero -> 512 real),
// packed-real trick, fused + x bias, final ortho scale. 8 rows per block;
// swizzled LDS tile gathers the strided A[c][k][h0..h0+7] reads in 64B chunks.
// Matches numpy irfft: imaginary part of DC bin is ignored (zeroed).
// ---------------------------------------------------------------------------
__global__ __launch_bounds__(512) void k5_irfftw(const float2* __restrict__ A,
                                                 const float* __restrict__ x,
                                                 float* __restrict__ out) {
    __shared__ float2 b0[8][256];
    __shared__ float2 b1[8][256];
    __shared__ float2 tile[KW * 8];
    __shared__ float2 tw[255];
    __shared__ float2 ctw[256];

    int tid = threadIdx.x;
    gen_tw(tw, tid, 512, 1.0f);
    for (int f = tid; f < 256; f += 512) {
        float sn, cs;
        __sincosf(6.283185307179586f * (float)f / 512.0f, &sn, &cs);
        ctw[f] = make_float2(cs, sn);
    }

    int blk = blockIdx.x;
    int c = blk >> 5;
    int h0 = (blk & 31) << 3;

    for (int idx = tid; idx < KW * 8; idx += 512) {
        int k = idx >> 3;
        int r2 = idx & 7;
        tile[TSWZ(idx)] = A[((size_t)c * KW + k) * HH + h0 + r2];
    }
    __syncthreads();

    int r = tid >> 6;
    int lane = tid & 63;
    int h = h0 + r;
    float2* s0 = b0[r];
    float2* s1 = b1[r];

    // Zhat[k] = Xe[k] + i*Xo[k], k = 0..255
    for (int k = lane; k < 256; k += 64) {
        float2 P = make_float2(0.f, 0.f);
        float2 Q = make_float2(0.f, 0.f);
        if (k <= 128) {
            P = tile[TSWZ(k * 8 + r)];
            if (k == 0) P.y = 0.f;            // numpy irfft drops Im(DC)
        }
        if (k >= 128) {                        // X[k+256] = conj(X[256-k])
            float2 qv = tile[TSWZ((256 - k) * 8 + r)];
            Q = make_float2(qv.x, -qv.y);
        }
        float2 Xe = make_float2(0.5f * (P.x + Q.x), 0.5f * (P.y + Q.y));
        float2 d = make_float2(0.5f * (P.x - Q.x), 0.5f * (P.y - Q.y));
        float2 Xo = cmul(d, ctw[k]);
        s0[SWZ(k)] = make_float2(Xe.x - Xo.y, Xe.y + Xo.x);
    }
    __syncthreads();

    fft256x4(s0, s1, tw, lane);   // unnormalized inverse, result in s0

    const float4* xr = (const float4*)(x + ((size_t)c * HH + h) * WW);
    float4* orow = (float4*)(out + ((size_t)c * HH + h) * WW);
    for (int m = lane; m < 128; m += 64) {
        float2 z0 = s0[SWZ(2 * m)];
        float2 z1 = s0[SWZ(2 * m + 1)];
        float4 xv = xr[m];
        orow[m] = make_float4(fmaf(SI, z0.x, xv.x), fmaf(SI, z0.y, xv.y),
                              fmaf(SI, z1.x, xv.z), fmaf(SI, z1.y, xv.w));
    }
}

// ---------------------------------------------------------------------------
extern "C" void kernel_launch(void* const* d_in, const int* in_sizes, int n_in,
                              void* d_out, int out_size, void* d_ws, size_t ws_size,
                              hipStream_t stream) {
    const float* x = (const float*)d_in[0];
    const float2* w1 = (const float2*)d_in[1];
    const float2* b1 = (const float2*)d_in[2];
    const float2* w2 = (const float2*)d_in[3];
    const float2* b2 = (const float2*)d_in[4];
    float* out = (float*)d_out;
    float2* A = (float2*)d_ws;   // [768][129][256] complex = 202,899,456 bytes

    k1_rfftw<<<dim3(CC * HH / 8), dim3(512), 0, stream>>>(x, A);
    k_colfft<-1><<<dim3(CC * KW / 4), dim3(256), 0, stream>>>(A);
    k3_mlp<<<dim3(NB * (MPC / K3M)), dim3(512), 0, stream>>>(A, w1, b1, w2, b2);
    k_colfft<1><<<dim3(CC * KW / 4), dim3(256), 0, stream>>>(A);
    k5_irfftw<<<dim3(CC * HH / 8), dim3(512), 0, stream>>>(A, x, out);
}

// Round 2
// 1848.124 us; speedup vs baseline: 1.2065x; 1.2065x over previous
//
#include <hip/hip_runtime.h>
#include <math.h>

#define HH 256
#define WW 512
#define CC 768
#define KW 129            // kept W modes (0..128)
#define NB 8
#define BS 96
#define MPC (KW*HH)       // modes per channel = 33024
#define K3M 64            // modes per K3 block

constexpr float SF = 0.00276213586400528f;   // 1/sqrt(131072)  forward ortho
constexpr float SI = 0.00552427172801056f;   // 2/sqrt(131072)  inverse ortho (x2 from packing)
constexpr float LAM = 0.01f;

// XOR swizzle for the 256-entry FFT buffers: kills the 8-way write conflicts of
// early Stockham stages while keeping contiguous runs >=16 conflict-free.
#define SWZ(i) ((i) ^ (((i) >> 4) & 0xF))
// Swizzle for the [k][r] transpose tile (stride-8-float2 access across k lanes
// was a 16-way conflict): spread bits 4..7 into bits 1..3 and bit 7 into bit 0.
#define TSWZ(i) ((i) ^ ((((i) >> 4) & 7) << 1) ^ (((i) >> 7) & 1))

__device__ inline float2 cadd(float2 a, float2 b) { return make_float2(a.x + b.x, a.y + b.y); }
__device__ inline float2 csub(float2 a, float2 b) { return make_float2(a.x - b.x, a.y - b.y); }
__device__ inline float2 cmul(float2 a, float2 b) {
    return make_float2(a.x * b.x - a.y * b.y, a.x * b.y + a.y * b.x);
}

// ---------------------------------------------------------------------------
// Twiddle table: radix-2 stage s in [0,8), m = 128>>s entries,
// tw[off(s)+p] = e^{sign*2*pi*i*p/(256>>s)}.  off = 0,128,192,224,240,248,252,254.
// Generated once per block (255 sincos total, vs 1024 per FFT row before).
// ---------------------------------------------------------------------------
__device__ inline void gen_tw(float2* tw, int tid, int nthr, float sign) {
    for (int f = tid; f < 255; f += nthr) {
        int fm = f, n = 256;
        while (fm >= (n >> 1)) { fm -= (n >> 1); n >>= 1; }
        float sn, cs;
        __sincosf(sign * 6.283185307179586f * (float)fm / (float)n, &sn, &cs);
        tw[f] = make_float2(cs, sn);
    }
}

// ---------------------------------------------------------------------------
// 256-point Stockham FFT, two radix-2 stages fused per pass (register radix-4):
// stage s writes {d1, d1+ls, d1+128, d1+128+ls} which are exactly stage s+1's
// read pairs, so the pair runs entirely in registers. 4 barriers instead of 8,
// half the LDS traffic. One 64-lane wave per row; result lands in s0.
// Twiddle sign is baked into the table.
// ---------------------------------------------------------------------------
__device__ inline void fft256x4(float2* s0, float2* s1, const float2* tw, int lane) {
    float2* src = s0;
    float2* dst = s1;
    int logls = 0;
    int offA = 0;
#pragma unroll
    for (int j = 0; j < 4; j++) {
        int ls = 1 << logls;            // 1,4,16,64
        int hm = 64 >> logls;           // 64/ls = entries of stage B
        int offB = offA + (128 >> logls);
        int q = lane & (ls - 1);
        int p = lane >> logls;
        float2 a0 = src[SWZ(lane)];
        float2 a1 = src[SWZ(lane + 64)];
        float2 a2 = src[SWZ(lane + 128)];
        float2 a3 = src[SWZ(lane + 192)];
        float2 wA0 = tw[offA + p];
        float2 wA1 = tw[offA + p + hm];
        float2 wB  = tw[offB + p];
        // stage A (n = 256>>2j): butterflies at lane and lane+64
        float2 e0 = cadd(a0, a2);
        float2 e1 = cmul(csub(a0, a2), wA0);
        float2 e2 = cadd(a1, a3);
        float2 e3 = cmul(csub(a1, a3), wA1);
        // stage B (n/2): butterflies at d1 and d1+ls, both twiddle index p
        float2 f0 = cadd(e0, e2);
        float2 f1 = cmul(csub(e0, e2), wB);
        float2 f2 = cadd(e1, e3);
        float2 f3 = cmul(csub(e1, e3), wB);
        int o = q + ((p << logls) << 2);  // q + 4*p*ls
        dst[SWZ(o)]          = f0;
        dst[SWZ(o + ls)]     = f2;
        dst[SWZ(o + 2 * ls)] = f1;
        dst[SWZ(o + 3 * ls)] = f3;
        __syncthreads();
        float2* tmp = src; src = dst; dst = tmp;
        offA = offB + hm;
        logls += 2;
    }
}

// ---------------------------------------------------------------------------
// K1: forward real FFT along W (512 real -> 129 complex), packed-real trick.
// 8 rows (one wave each) per block; swizzled LDS tile-transpose so the output
// A[c][k][h] (h contiguous) is written in 64B chunks.
// ---------------------------------------------------------------------------
__global__ __launch_bounds__(512) void k1_rfftw(const float* __restrict__ x,
                                                float2* __restrict__ A) {
    __shared__ float2 b0[8][256];
    __shared__ float2 b1[8][256];
    __shared__ float2 tile[KW * 8];
    __shared__ float2 tw[255];
    __shared__ float2 ctw[129];

    int tid = threadIdx.x;
    gen_tw(tw, tid, 512, -1.0f);
    for (int f = tid; f < 129; f += 512) {
        float sn, cs;
        __sincosf(-6.283185307179586f * (float)f / 512.0f, &sn, &cs);
        ctw[f] = make_float2(cs, sn);
    }

    int r = tid >> 6;            // row 0..7 (= wave id)
    int lane = tid & 63;
    int blk = blockIdx.x;        // 0..24575
    int c = blk >> 5;            // channel
    int h0 = (blk & 31) << 3;    // first h of this block
    int h = h0 + r;

    const float4* xrow = (const float4*)(x + ((size_t)c * HH + h) * WW);
    float2* s0 = b0[r];
    float2* s1 = b1[r];

    // pack: z[n] = x[2n] + i x[2n+1], scaled by forward ortho factor
    for (int n = lane; n < 128; n += 64) {
        float4 v = xrow[n];
        s0[SWZ(2 * n)]     = make_float2(v.x * SF, v.y * SF);
        s0[SWZ(2 * n + 1)] = make_float2(v.z * SF, v.w * SF);
    }
    __syncthreads();

    fft256x4(s0, s1, tw, lane);

    // combine to X[k], k = 0..128
    for (int k = lane; k <= 128; k += 64) {
        float2 Za = s0[SWZ(k & 255)];
        float2 Zb = s0[SWZ((256 - k) & 255)];
        // Xe = 0.5(Za + conj(Zb)); Xo = -0.5i(Za - conj(Zb))
        float2 Xe = make_float2(0.5f * (Za.x + Zb.x), 0.5f * (Za.y - Zb.y));
        float dx = Za.x - Zb.x;
        float dy = Za.y + Zb.y;
        float2 Xo = make_float2(0.5f * dy, -0.5f * dx);
        float2 X = cadd(Xe, cmul(Xo, ctw[k]));
        tile[TSWZ(k * 8 + r)] = X;
    }
    __syncthreads();

    for (int idx = tid; idx < KW * 8; idx += 512) {
        int k = idx >> 3;
        int r2 = idx & 7;
        A[((size_t)c * KW + k) * HH + h0 + r2] = tile[TSWZ(idx)];
    }
}

// ---------------------------------------------------------------------------
// K2/K4: 256-pt complex FFT along H, in place. A flat = [c][k][h], each column
// is 256 contiguous float2. 4 columns (one wave each) per 256-thread block.
// ---------------------------------------------------------------------------
template <int SIGN>
__global__ __launch_bounds__(256) void k_colfft(float2* __restrict__ A) {
    __shared__ float2 b0[4][256];
    __shared__ float2 b1[4][256];
    __shared__ float2 tw[255];
    int tid = threadIdx.x;
    gen_tw(tw, tid, 256, (float)SIGN);
    int col = tid >> 6;          // 0..3 (= wave id)
    int lane = tid & 63;
    size_t base = ((size_t)blockIdx.x * 4 + col) * 256;
    float2* s0 = b0[col];
    float2* s1 = b1[col];
    const float4* Ai = (const float4*)(A + base);
    for (int n = lane; n < 128; n += 64) {
        float4 v = Ai[n];
        s0[SWZ(2 * n)]     = make_float2(v.x, v.y);
        s0[SWZ(2 * n + 1)] = make_float2(v.z, v.w);
    }
    __syncthreads();
    fft256x4(s0, s1, tw, lane);
    float4* Ao = (float4*)(A + base);
    for (int n = lane; n < 128; n += 64) {
        float2 z0 = s0[SWZ(2 * n)];
        float2 z1 = s0[SWZ(2 * n + 1)];
        Ao[n] = make_float4(z0.x, z0.y, z1.x, z1.y);
    }
}

// ---------------------------------------------------------------------------
// K3: per-mode complex MLP, in place on A. One block = one channel-block bk and
// 64 modes; 512 threads = 8 waves. Per 16-output phase the needed weight
// columns are staged into LDS (wt[16][97], +1 pad -> staging writes at the b64
// conflict floor), so the inner loop is pure in-order LDS traffic:
// 1 per-lane a-read + 2 wave-uniform broadcast w-reads + 8 FMAs. This removes
// the s_load/ds_read lgkmcnt(0) serialization that stalled v1 (VALUBusy 21%).
// ---------------------------------------------------------------------------
__global__ __launch_bounds__(512) void k3_mlp(float2* __restrict__ A,
                                              const float2* __restrict__ w1,
                                              const float2* __restrict__ b1,
                                              const float2* __restrict__ w2,
                                              const float2* __restrict__ b2) {
    __shared__ float2 tile[BS][K3M];   // 96 x 64 complex = 48 KB, a then hidden
    __shared__ float2 wt[16][BS + 1];  // 16 weight cols, +1 pad = 12.1 KB
    int tid = threadIdx.x;
    int bk = blockIdx.x / (MPC / K3M);           // 0..7
    int m0 = (blockIdx.x % (MPC / K3M)) * K3M;   // mode tile origin
    int t = tid & 63;
    int osub = tid >> 6;    // 0..7, wave id

    for (int idx = tid; idx < BS * (K3M / 2); idx += 512) {
        int i = idx >> 5;
        int tt = idx & 31;
        float4 v = *(const float4*)(A + ((size_t)(bk * BS + i)) * MPC + m0 + 2 * tt);
        tile[i][2 * tt]     = make_float2(v.x, v.y);
        tile[i][2 * tt + 1] = make_float2(v.z, v.w);
    }

    const float2* w1b = w1 + (size_t)bk * BS * BS;
    const float2* b1b = b1 + (size_t)bk * BS;
    const float2* w2b = w2 + (size_t)bk * BS * BS;
    const float2* b2b = b2 + (size_t)bk * BS;

    float2 hreg[12];
    // ---- layer 1: h = relu(W1^T a + b1) ----
#pragma unroll
    for (int rr = 0; rr < 6; rr++) {
        int o0 = rr * 16;
        __syncthreads();   // prev phase done with wt (and, at rr=0, tile staged)
        for (int idx = tid; idx < 16 * BS; idx += 512) {
            int i = idx >> 4;          // 0..95
            int j = idx & 15;          // 0..15  (consecutive lanes -> 128B runs)
            wt[j][i] = w1b[i * BS + o0 + j];
        }
        __syncthreads();
        int o1 = __builtin_amdgcn_readfirstlane(o0 + osub);   // wave-uniform
        float2 acc1 = b1b[o1];
        float2 acc2 = b1b[o1 + 8];
#pragma unroll 8
        for (int i = 0; i < BS; i++) {
            float2 a  = tile[i][t];
            float2 wA = wt[osub][i];
            float2 wB = wt[osub + 8][i];
            acc1.x = fmaf(a.x, wA.x, fmaf(-a.y, wA.y, acc1.x));
            acc1.y = fmaf(a.x, wA.y, fmaf(a.y, wA.x, acc1.y));
            acc2.x = fmaf(a.x, wB.x, fmaf(-a.y, wB.y, acc2.x));
            acc2.y = fmaf(a.x, wB.y, fmaf(a.y, wB.x, acc2.y));
        }
        hreg[2 * rr]     = make_float2(fmaxf(acc1.x, 0.f), fmaxf(acc1.y, 0.f));
        hreg[2 * rr + 1] = make_float2(fmaxf(acc2.x, 0.f), fmaxf(acc2.y, 0.f));
    }
    __syncthreads();   // all waves done reading a-tile
#pragma unroll
    for (int rr = 0; rr < 6; rr++) {
        tile[rr * 16 + osub][t]     = hreg[2 * rr];
        tile[rr * 16 + 8 + osub][t] = hreg[2 * rr + 1];
    }

    // ---- layer 2: s = softshrink(W2^T h + b2) ----
#pragma unroll
    for (int rr = 0; rr < 6; rr++) {
        int o0 = rr * 16;
        __syncthreads();   // h-writes visible (rr=0) / prev phase done with wt
        for (int idx = tid; idx < 16 * BS; idx += 512) {
            int i = idx >> 4;
            int j = idx & 15;
            wt[j][i] = w2b[i * BS + o0 + j];
        }
        __syncthreads();
        int o1 = __builtin_amdgcn_readfirstlane(o0 + osub);
        float2 acc1 = b2b[o1];
        float2 acc2 = b2b[o1 + 8];
#pragma unroll 8
        for (int i = 0; i < BS; i++) {
            float2 a  = tile[i][t];
            float2 wA = wt[osub][i];
            float2 wB = wt[osub + 8][i];
            acc1.x = fmaf(a.x, wA.x, fmaf(-a.y, wA.y, acc1.x));
            acc1.y = fmaf(a.x, wA.y, fmaf(a.y, wA.x, acc1.y));
            acc2.x = fmaf(a.x, wB.x, fmaf(-a.y, wB.y, acc2.x));
            acc2.y = fmaf(a.x, wB.y, fmaf(a.y, wB.x, acc2.y));
        }
        float r1x = fmaxf(fabsf(acc1.x) - LAM, 0.f);
        float r1y = fmaxf(fabsf(acc1.y) - LAM, 0.f);
        float r2x = fmaxf(fabsf(acc2.x) - LAM, 0.f);
        float r2y = fmaxf(fabsf(acc2.y) - LAM, 0.f);
        float2 s1v = make_float2(copysignf(r1x, acc1.x), copysignf(r1y, acc1.y));
        float2 s2v = make_float2(copysignf(r2x, acc2.x), copysignf(r2y, acc2.y));
        A[((size_t)(bk * BS + o1)) * MPC + m0 + t]     = s1v;
        A[((size_t)(bk * BS + o1 + 8)) * MPC + m0 + t] = s2v;
    }
}

// ---------------------------------------------------------------------------
// K5: inverse real FFT along W (129 complex modes, rest zero -> 512 real),
// packed-real trick, fused + x bias, final ortho scale. 8 rows per block;
// swizzled LDS tile gathers the strided A[c][k][h0..h0+7] reads in 64B chunks.
// Matches numpy irfft: imaginary part of DC bin is ignored (zeroed).
// ---------------------------------------------------------------------------
__global__ __launch_bounds__(512) void k5_irfftw(const float2* __restrict__ A,
                                                 const float* __restrict__ x,
                                                 float* __restrict__ out) {
    __shared__ float2 b0[8][256];
    __shared__ float2 b1[8][256];
    __shared__ float2 tile[KW * 8];
    __shared__ float2 tw[255];
    __shared__ float2 ctw[256];

    int tid = threadIdx.x;
    gen_tw(tw, tid, 512, 1.0f);
    for (int f = tid; f < 256; f += 512) {
        float sn, cs;
        __sincosf(6.283185307179586f * (float)f / 512.0f, &sn, &cs);
        ctw[f] = make_float2(cs, sn);
    }

    int blk = blockIdx.x;
    int c = blk >> 5;
    int h0 = (blk & 31) << 3;

    for (int idx = tid; idx < KW * 8; idx += 512) {
        int k = idx >> 3;
        int r2 = idx & 7;
        tile[TSWZ(idx)] = A[((size_t)c * KW + k) * HH + h0 + r2];
    }
    __syncthreads();

    int r = tid >> 6;
    int lane = tid & 63;
    int h = h0 + r;
    float2* s0 = b0[r];
    float2* s1 = b1[r];

    // Zhat[k] = Xe[k] + i*Xo[k], k = 0..255
    for (int k = lane; k < 256; k += 64) {
        float2 P = make_float2(0.f, 0.f);
        float2 Q = make_float2(0.f, 0.f);
        if (k <= 128) {
            P = tile[TSWZ(k * 8 + r)];
            if (k == 0) P.y = 0.f;            // numpy irfft drops Im(DC)
        }
        if (k >= 128) {                        // X[k+256] = conj(X[256-k])
            float2 qv = tile[TSWZ((256 - k) * 8 + r)];
            Q = make_float2(qv.x, -qv.y);
        }
        float2 Xe = make_float2(0.5f * (P.x + Q.x), 0.5f * (P.y + Q.y));
        float2 d = make_float2(0.5f * (P.x - Q.x), 0.5f * (P.y - Q.y));
        float2 Xo = cmul(d, ctw[k]);
        s0[SWZ(k)] = make_float2(Xe.x - Xo.y, Xe.y + Xo.x);
    }
    __syncthreads();

    fft256x4(s0, s1, tw, lane);   // unnormalized inverse, result in s0

    const float4* xr = (const float4*)(x + ((size_t)c * HH + h) * WW);
    float4* orow = (float4*)(out + ((size_t)c * HH + h) * WW);
    for (int m = lane; m < 128; m += 64) {
        float2 z0 = s0[SWZ(2 * m)];
        float2 z1 = s0[SWZ(2 * m + 1)];
        float4 xv = xr[m];
        orow[m] = make_float4(fmaf(SI, z0.x, xv.x), fmaf(SI, z0.y, xv.y),
                              fmaf(SI, z1.x, xv.z), fmaf(SI, z1.y, xv.w));
    }
}

// ---------------------------------------------------------------------------
extern "C" void kernel_launch(void* const* d_in, const int* in_sizes, int n_in,
                              void* d_out, int out_size, void* d_ws, size_t ws_size,
                              hipStream_t stream) {
    const float* x = (const float*)d_in[0];
    const float2* w1 = (const float2*)d_in[1];
    const float2* b1 = (const float2*)d_in[2];
    const float2* w2 = (const float2*)d_in[3];
    const float2* b2 = (const float2*)d_in[4];
    float* out = (float*)d_out;
    float2* A = (float2*)d_ws;   // [768][129][256] complex = 202,899,456 bytes

    k1_rfftw<<<dim3(CC * HH / 8), dim3(512), 0, stream>>>(x, A);
    k_colfft<-1><<<dim3(CC * KW / 4), dim3(256), 0, stream>>>(A);
    k3_mlp<<<dim3(NB * (MPC / K3M)), dim3(512), 0, stream>>>(A, w1, b1, w2, b2);
    k_colfft<1><<<dim3(CC * KW / 4), dim3(256), 0, stream>>>(A);
    k5_irfftw<<<dim3(CC * HH / 8), dim3(512), 0, stream>>>(A, x, out);
}

// Round 3
// 1524.364 us; speedup vs baseline: 1.4628x; 1.2124x over previous
//
#include <hip/hip_runtime.h>
#include <math.h>

#define HH 256
#define WW 512
#define CC 768
#define KW 129            // kept W modes (0..128)
#define NB 8
#define BS 96
#define MPC (KW*HH)       // modes per channel = 33024
#define K3M 64            // modes per K3 block

constexpr float SF = 0.00276213586400528f;   // 1/sqrt(131072)  forward ortho
constexpr float SI = 0.00552427172801056f;   // 2/sqrt(131072)  inverse ortho (x2 from packing)
constexpr float LAM = 0.01f;

// XOR swizzle for the 256-entry FFT buffers: kills the 8-way write conflicts of
// early Stockham stages while keeping contiguous runs >=16 conflict-free.
#define SWZ(i) ((i) ^ (((i) >> 4) & 0xF))
// Swizzle for the [k][r] transpose tile (stride-8-float2 access across k lanes
// was a 16-way conflict): spread bits 4..7 into bits 1..3 and bit 7 into bit 0.
#define TSWZ(i) ((i) ^ ((((i) >> 4) & 7) << 1) ^ (((i) >> 7) & 1))

__device__ inline float2 cadd(float2 a, float2 b) { return make_float2(a.x + b.x, a.y + b.y); }
__device__ inline float2 csub(float2 a, float2 b) { return make_float2(a.x - b.x, a.y - b.y); }
__device__ inline float2 cmul(float2 a, float2 b) {
    return make_float2(a.x * b.x - a.y * b.y, a.x * b.y + a.y * b.x);
}

// ---------------------------------------------------------------------------
// Twiddle table: radix-2 stage s in [0,8), m = 128>>s entries,
// tw[off(s)+p] = e^{sign*2*pi*i*p/(256>>s)}.  off = 0,128,192,224,240,248,252,254.
// ---------------------------------------------------------------------------
__device__ inline void gen_tw(float2* tw, int tid, int nthr, float sign) {
    for (int f = tid; f < 255; f += nthr) {
        int fm = f, n = 256;
        while (fm >= (n >> 1)) { fm -= (n >> 1); n >>= 1; }
        float sn, cs;
        __sincosf(sign * 6.283185307179586f * (float)fm / (float)n, &sn, &cs);
        tw[f] = make_float2(cs, sn);
    }
}

// ---------------------------------------------------------------------------
// 256-point Stockham FFT, two radix-2 stages fused per pass (register radix-4):
// 4 barriers instead of 8, half the LDS traffic. One 64-lane wave per row.
// ---------------------------------------------------------------------------
__device__ inline void fft256x4(float2* s0, float2* s1, const float2* tw, int lane) {
    float2* src = s0;
    float2* dst = s1;
    int logls = 0;
    int offA = 0;
#pragma unroll
    for (int j = 0; j < 4; j++) {
        int ls = 1 << logls;            // 1,4,16,64
        int hm = 64 >> logls;           // 64/ls = entries of stage B
        int offB = offA + (128 >> logls);
        int q = lane & (ls - 1);
        int p = lane >> logls;
        float2 a0 = src[SWZ(lane)];
        float2 a1 = src[SWZ(lane + 64)];
        float2 a2 = src[SWZ(lane + 128)];
        float2 a3 = src[SWZ(lane + 192)];
        float2 wA0 = tw[offA + p];
        float2 wA1 = tw[offA + p + hm];
        float2 wB  = tw[offB + p];
        float2 e0 = cadd(a0, a2);
        float2 e1 = cmul(csub(a0, a2), wA0);
        float2 e2 = cadd(a1, a3);
        float2 e3 = cmul(csub(a1, a3), wA1);
        float2 f0 = cadd(e0, e2);
        float2 f1 = cmul(csub(e0, e2), wB);
        float2 f2 = cadd(e1, e3);
        float2 f3 = cmul(csub(e1, e3), wB);
        int o = q + ((p << logls) << 2);  // q + 4*p*ls
        dst[SWZ(o)]          = f0;
        dst[SWZ(o + ls)]     = f2;
        dst[SWZ(o + 2 * ls)] = f1;
        dst[SWZ(o + 3 * ls)] = f3;
        __syncthreads();
        float2* tmp = src; src = dst; dst = tmp;
        offA = offB + hm;
        logls += 2;
    }
}

// ---------------------------------------------------------------------------
// K1: forward real FFT along W (512 real -> 129 complex), packed-real trick.
// ---------------------------------------------------------------------------
__global__ __launch_bounds__(512) void k1_rfftw(const float* __restrict__ x,
                                                float2* __restrict__ A) {
    __shared__ float2 b0[8][256];
    __shared__ float2 b1[8][256];
    __shared__ float2 tile[KW * 8];
    __shared__ float2 tw[255];
    __shared__ float2 ctw[129];

    int tid = threadIdx.x;
    gen_tw(tw, tid, 512, -1.0f);
    for (int f = tid; f < 129; f += 512) {
        float sn, cs;
        __sincosf(-6.283185307179586f * (float)f / 512.0f, &sn, &cs);
        ctw[f] = make_float2(cs, sn);
    }

    int r = tid >> 6;            // row 0..7 (= wave id)
    int lane = tid & 63;
    int blk = blockIdx.x;        // 0..24575
    int c = blk >> 5;            // channel
    int h0 = (blk & 31) << 3;    // first h of this block
    int h = h0 + r;

    const float4* xrow = (const float4*)(x + ((size_t)c * HH + h) * WW);
    float2* s0 = b0[r];
    float2* s1 = b1[r];

    for (int n = lane; n < 128; n += 64) {
        float4 v = xrow[n];
        s0[SWZ(2 * n)]     = make_float2(v.x * SF, v.y * SF);
        s0[SWZ(2 * n + 1)] = make_float2(v.z * SF, v.w * SF);
    }
    __syncthreads();

    fft256x4(s0, s1, tw, lane);

    for (int k = lane; k <= 128; k += 64) {
        float2 Za = s0[SWZ(k & 255)];
        float2 Zb = s0[SWZ((256 - k) & 255)];
        float2 Xe = make_float2(0.5f * (Za.x + Zb.x), 0.5f * (Za.y - Zb.y));
        float dx = Za.x - Zb.x;
        float dy = Za.y + Zb.y;
        float2 Xo = make_float2(0.5f * dy, -0.5f * dx);
        float2 X = cadd(Xe, cmul(Xo, ctw[k]));
        tile[TSWZ(k * 8 + r)] = X;
    }
    __syncthreads();

    for (int idx = tid; idx < KW * 8; idx += 512) {
        int k = idx >> 3;
        int r2 = idx & 7;
        A[((size_t)c * KW + k) * HH + h0 + r2] = tile[TSWZ(idx)];
    }
}

// ---------------------------------------------------------------------------
// K2/K4: 256-pt complex FFT along H, in place. 4 columns per 256-thread block.
// ---------------------------------------------------------------------------
template <int SIGN>
__global__ __launch_bounds__(256) void k_colfft(float2* __restrict__ A) {
    __shared__ float2 b0[4][256];
    __shared__ float2 b1[4][256];
    __shared__ float2 tw[255];
    int tid = threadIdx.x;
    gen_tw(tw, tid, 256, (float)SIGN);
    int col = tid >> 6;          // 0..3 (= wave id)
    int lane = tid & 63;
    size_t base = ((size_t)blockIdx.x * 4 + col) * 256;
    float2* s0 = b0[col];
    float2* s1 = b1[col];
    const float4* Ai = (const float4*)(A + base);
    for (int n = lane; n < 128; n += 64) {
        float4 v = Ai[n];
        s0[SWZ(2 * n)]     = make_float2(v.x, v.y);
        s0[SWZ(2 * n + 1)] = make_float2(v.z, v.w);
    }
    __syncthreads();
    fft256x4(s0, s1, tw, lane);
    float4* Ao = (float4*)(A + base);
    for (int n = lane; n < 128; n += 64) {
        float2 z0 = s0[SWZ(2 * n)];
        float2 z1 = s0[SWZ(2 * n + 1)];
        Ao[n] = make_float4(z0.x, z0.y, z1.x, z1.y);
    }
}

// ---------------------------------------------------------------------------
// K3 v3: per-mode complex MLP. Round-2 PMC showed the CU LDS pipe saturated
// 3:1 over VALU (3 ds_reads per 8 FMA-inst). v3 cuts LDS issue 2.6x per MAC:
// each wave computes 4 outputs (N_o=4) so one K-step is {1x ds_read_b64 (a) +
// 2x ds_read_b128 broadcast (4 complex weights)} feeding 16 FMAs. Weight tile
// wt[96][32] packs a phase's 32 output columns so the 4 weights sit in 32
// contiguous bytes. 48+24=72 KB LDS -> 2 blocks/CU (4 waves/SIMD) restores
// the occupancy lost in round 2.
// ---------------------------------------------------------------------------
__global__ __launch_bounds__(512, 4) void k3_mlp(float2* __restrict__ A,
                                                 const float2* __restrict__ w1,
                                                 const float2* __restrict__ b1,
                                                 const float2* __restrict__ w2,
                                                 const float2* __restrict__ b2) {
    __shared__ float2 tile[BS][K3M];   // 96 x 64 complex = 48 KB, a then hidden
    __shared__ float2 wt[BS][32];      // one phase's 32 weight columns = 24 KB
    int tid = threadIdx.x;
    int bk = blockIdx.x / (MPC / K3M);           // 0..7
    int m0 = (blockIdx.x % (MPC / K3M)) * K3M;   // mode tile origin
    int t = tid & 63;
    int osu = __builtin_amdgcn_readfirstlane(tid >> 6);  // wave id 0..7
    int ob = osu * 4;                                    // wave's 4 outputs in phase

    // stage a-tile (each row = 64 consecutive modes, float4 loads)
    for (int idx = tid; idx < BS * (K3M / 2); idx += 512) {
        int i = idx >> 5;
        int tt = idx & 31;
        float4 v = *(const float4*)(A + ((size_t)(bk * BS + i)) * MPC + m0 + 2 * tt);
        tile[i][2 * tt]     = make_float2(v.x, v.y);
        tile[i][2 * tt + 1] = make_float2(v.z, v.w);
    }

    const float2* w1b = w1 + (size_t)bk * BS * BS;
    const float2* b1b = b1 + (size_t)bk * BS;
    const float2* w2b = w2 + (size_t)bk * BS * BS;
    const float2* b2b = b2 + (size_t)bk * BS;

    float2 hreg[12];
    // ---- layer 1: h = relu(W1^T a + b1), 3 phases x 32 outputs ----
#pragma unroll
    for (int ph = 0; ph < 3; ph++) {
        int o0 = ph * 32;
        __syncthreads();   // prev phase done with wt (ph=0: tile staged)
        for (int idx = tid; idx < BS * 32; idx += 512) {
            int i = idx >> 5;          // 0..95
            int j = idx & 31;          // consecutive lanes -> 256B runs
            wt[i][j] = w1b[i * BS + o0 + j];
        }
        __syncthreads();
        float2 acc0 = b1b[o0 + ob];
        float2 acc1 = b1b[o0 + ob + 1];
        float2 acc2 = b1b[o0 + ob + 2];
        float2 acc3 = b1b[o0 + ob + 3];
#pragma unroll 8
        for (int i = 0; i < BS; i++) {
            float2 a  = tile[i][t];
            float4 w01 = *(const float4*)&wt[i][ob];       // outputs ob, ob+1
            float4 w23 = *(const float4*)&wt[i][ob + 2];   // outputs ob+2, ob+3
            acc0.x = fmaf(a.x, w01.x, fmaf(-a.y, w01.y, acc0.x));
            acc0.y = fmaf(a.x, w01.y, fmaf(a.y, w01.x, acc0.y));
            acc1.x = fmaf(a.x, w01.z, fmaf(-a.y, w01.w, acc1.x));
            acc1.y = fmaf(a.x, w01.w, fmaf(a.y, w01.z, acc1.y));
            acc2.x = fmaf(a.x, w23.x, fmaf(-a.y, w23.y, acc2.x));
            acc2.y = fmaf(a.x, w23.y, fmaf(a.y, w23.x, acc2.y));
            acc3.x = fmaf(a.x, w23.z, fmaf(-a.y, w23.w, acc3.x));
            acc3.y = fmaf(a.x, w23.w, fmaf(a.y, w23.z, acc3.y));
        }
        hreg[ph * 4 + 0] = make_float2(fmaxf(acc0.x, 0.f), fmaxf(acc0.y, 0.f));
        hreg[ph * 4 + 1] = make_float2(fmaxf(acc1.x, 0.f), fmaxf(acc1.y, 0.f));
        hreg[ph * 4 + 2] = make_float2(fmaxf(acc2.x, 0.f), fmaxf(acc2.y, 0.f));
        hreg[ph * 4 + 3] = make_float2(fmaxf(acc3.x, 0.f), fmaxf(acc3.y, 0.f));
    }
    __syncthreads();   // all waves done reading a-tile
#pragma unroll
    for (int ph = 0; ph < 3; ph++) {
        int o = ph * 32 + ob;
        tile[o][t]     = hreg[ph * 4 + 0];
        tile[o + 1][t] = hreg[ph * 4 + 1];
        tile[o + 2][t] = hreg[ph * 4 + 2];
        tile[o + 3][t] = hreg[ph * 4 + 3];
    }

    // ---- layer 2: s = softshrink(W2^T h + b2), 3 phases x 32 outputs ----
#pragma unroll
    for (int ph = 0; ph < 3; ph++) {
        int o0 = ph * 32;
        __syncthreads();   // h-writes visible (ph=0) / prev phase done with wt
        for (int idx = tid; idx < BS * 32; idx += 512) {
            int i = idx >> 5;
            int j = idx & 31;
            wt[i][j] = w2b[i * BS + o0 + j];
        }
        __syncthreads();
        float2 acc0 = b2b[o0 + ob];
        float2 acc1 = b2b[o0 + ob + 1];
        float2 acc2 = b2b[o0 + ob + 2];
        float2 acc3 = b2b[o0 + ob + 3];
#pragma unroll 8
        for (int i = 0; i < BS; i++) {
            float2 a  = tile[i][t];
            float4 w01 = *(const float4*)&wt[i][ob];
            float4 w23 = *(const float4*)&wt[i][ob + 2];
            acc0.x = fmaf(a.x, w01.x, fmaf(-a.y, w01.y, acc0.x));
            acc0.y = fmaf(a.x, w01.y, fmaf(a.y, w01.x, acc0.y));
            acc1.x = fmaf(a.x, w01.z, fmaf(-a.y, w01.w, acc1.x));
            acc1.y = fmaf(a.x, w01.w, fmaf(a.y, w01.z, acc1.y));
            acc2.x = fmaf(a.x, w23.x, fmaf(-a.y, w23.y, acc2.x));
            acc2.y = fmaf(a.x, w23.y, fmaf(a.y, w23.x, acc2.y));
            acc3.x = fmaf(a.x, w23.z, fmaf(-a.y, w23.w, acc3.x));
            acc3.y = fmaf(a.x, w23.w, fmaf(a.y, w23.z, acc3.y));
        }
        float2 accs[4] = {acc0, acc1, acc2, acc3};
#pragma unroll
        for (int j = 0; j < 4; j++) {
            float rx = fmaxf(fabsf(accs[j].x) - LAM, 0.f);
            float ry = fmaxf(fabsf(accs[j].y) - LAM, 0.f);
            float2 sv = make_float2(copysignf(rx, accs[j].x), copysignf(ry, accs[j].y));
            A[((size_t)(bk * BS + o0 + ob + j)) * MPC + m0 + t] = sv;
        }
    }
}

// ---------------------------------------------------------------------------
// K5: inverse real FFT along W (129 complex modes -> 512 real), + x bias.
// ---------------------------------------------------------------------------
__global__ __launch_bounds__(512) void k5_irfftw(const float2* __restrict__ A,
                                                 const float* __restrict__ x,
                                                 float* __restrict__ out) {
    __shared__ float2 b0[8][256];
    __shared__ float2 b1[8][256];
    __shared__ float2 tile[KW * 8];
    __shared__ float2 tw[255];
    __shared__ float2 ctw[256];

    int tid = threadIdx.x;
    gen_tw(tw, tid, 512, 1.0f);
    for (int f = tid; f < 256; f += 512) {
        float sn, cs;
        __sincosf(6.283185307179586f * (float)f / 512.0f, &sn, &cs);
        ctw[f] = make_float2(cs, sn);
    }

    int blk = blockIdx.x;
    int c = blk >> 5;
    int h0 = (blk & 31) << 3;

    for (int idx = tid; idx < KW * 8; idx += 512) {
        int k = idx >> 3;
        int r2 = idx & 7;
        tile[TSWZ(idx)] = A[((size_t)c * KW + k) * HH + h0 + r2];
    }
    __syncthreads();

    int r = tid >> 6;
    int lane = tid & 63;
    int h = h0 + r;
    float2* s0 = b0[r];
    float2* s1 = b1[r];

    for (int k = lane; k < 256; k += 64) {
        float2 P = make_float2(0.f, 0.f);
        float2 Q = make_float2(0.f, 0.f);
        if (k <= 128) {
            P = tile[TSWZ(k * 8 + r)];
            if (k == 0) P.y = 0.f;            // numpy irfft drops Im(DC)
        }
        if (k >= 128) {                        // X[k+256] = conj(X[256-k])
            float2 qv = tile[TSWZ((256 - k) * 8 + r)];
            Q = make_float2(qv.x, -qv.y);
        }
        float2 Xe = make_float2(0.5f * (P.x + Q.x), 0.5f * (P.y + Q.y));
        float2 d = make_float2(0.5f * (P.x - Q.x), 0.5f * (P.y - Q.y));
        float2 Xo = cmul(d, ctw[k]);
        s0[SWZ(k)] = make_float2(Xe.x - Xo.y, Xe.y + Xo.x);
    }
    __syncthreads();

    fft256x4(s0, s1, tw, lane);   // unnormalized inverse, result in s0

    const float4* xr = (const float4*)(x + ((size_t)c * HH + h) * WW);
    float4* orow = (float4*)(out + ((size_t)c * HH + h) * WW);
    for (int m = lane; m < 128; m += 64) {
        float2 z0 = s0[SWZ(2 * m)];
        float2 z1 = s0[SWZ(2 * m + 1)];
        float4 xv = xr[m];
        orow[m] = make_float4(fmaf(SI, z0.x, xv.x), fmaf(SI, z0.y, xv.y),
                              fmaf(SI, z1.x, xv.z), fmaf(SI, z1.y, xv.w));
    }
}

// ---------------------------------------------------------------------------
extern "C" void kernel_launch(void* const* d_in, const int* in_sizes, int n_in,
                              void* d_out, int out_size, void* d_ws, size_t ws_size,
                              hipStream_t stream) {
    const float* x = (const float*)d_in[0];
    const float2* w1 = (const float2*)d_in[1];
    const float2* b1 = (const float2*)d_in[2];
    const float2* w2 = (const float2*)d_in[3];
    const float2* b2 = (const float2*)d_in[4];
    float* out = (float*)d_out;
    float2* A = (float2*)d_ws;   // [768][129][256] complex = 202,899,456 bytes

    k1_rfftw<<<dim3(CC * HH / 8), dim3(512), 0, stream>>>(x, A);
    k_colfft<-1><<<dim3(CC * KW / 4), dim3(256), 0, stream>>>(A);
    k3_mlp<<<dim3(NB * (MPC / K3M)), dim3(512), 0, stream>>>(A, w1, b1, w2, b2);
    k_colfft<1><<<dim3(CC * KW / 4), dim3(256), 0, stream>>>(A);
    k5_irfftw<<<dim3(CC * HH / 8), dim3(512), 0, stream>>>(A, x, out);
}